// Round 2
// baseline (152.016 us; speedup 1.0000x reference)
//
#include <hip/hip_runtime.h>
#include <hip/hip_bf16.h>
#include <hip/hip_cooperative_groups.h>

// CACE message passing, fused. MAX_L=3 -> NL=20, N_RBF=8, RB=8, K=3 -> C=9,
// NB=5, CUTOFF=5.5, T_MP=1, MP_NORM=0.2, N=2000, E=50000. fp32 I/O.
// Round 8: k_nodeA + k_node2 fused into ONE cooperative kernel (grid sync).
//  - fp32 A buffer eliminated (Ab stays in registers across grid.sync):
//    saves 11.5 MB write + 11.5 MB read.
//  - B0 buffer eliminated (Bsh1 stays in LDS): saves 2.9 + 2.9 MB.
//  - one fewer dispatch (4 -> 3) + one fewer 2000-block drain/launch tail.
//  grid = ceil(N/2) = 1000 persistent blocks x 192 thr, nodes {bid, bid+G}.
//  __launch_bounds__(192,3) => VGPR<=168 => 4 blocks/CU => 1024 co-resident.
//  Occupancy-checked at launch; falls back to the proven 2-kernel path.
// Row (48 floats): [0:8] g, [8:16] fr, [16:36] ang, [36:45] enc, [45:48] pad.
// Edge rows CSR-sorted by recv (k_edge scatters to final slot via cursor).

#define CUTF 5.5f
#define MPNORM 0.2f

namespace cg = cooperative_groups;

__constant__ int   d_DEGS[20]  = {0,1,1,1,2,2,2,2,2,2,3,3,3,3,3,3,3,3,3,3};
__constant__ float d_MULTI[20] = {1,1,1,1,1,2,2,1,2,1,1,3,3,3,6,3,1,3,3,1};

// ---------- count + exclusive scan + cursor zero, one block (N<=2048) --------
__global__ __launch_bounds__(1024) void k_prep(const int* __restrict__ eidx,
                                               int* __restrict__ offs,
                                               int* __restrict__ cursor,
                                               int N, int E) {
  __shared__ int cnt[2048];
  __shared__ int part[1024];
  int t = threadIdx.x;
  cnt[t] = 0; cnt[t + 1024] = 0;
  for (int i = t; i < N; i += 1024) cursor[i] = 0;
  __syncthreads();
  const int* recv = eidx + E;
  if ((E & 3) == 0) {
    #pragma unroll 2
    for (int i = t * 4; i + 3 < E; i += 4096) {
      int4 v = *reinterpret_cast<const int4*>(recv + i);
      atomicAdd(&cnt[v.x], 1); atomicAdd(&cnt[v.y], 1);
      atomicAdd(&cnt[v.z], 1); atomicAdd(&cnt[v.w], 1);
    }
  } else {
    #pragma unroll 4
    for (int i = t; i < E; i += 1024) atomicAdd(&cnt[recv[i]], 1);
  }
  __syncthreads();
  int a = cnt[2 * t], b = cnt[2 * t + 1];
  int s = a + b;
  part[t] = s;
  __syncthreads();
  for (int d = 1; d < 1024; d <<= 1) {
    int add = (t >= d) ? part[t - d] : 0;
    __syncthreads();
    part[t] += add;
    __syncthreads();
  }
  int excl = part[t] - s;
  if (2 * t     < N) offs[2 * t]     = excl;
  if (2 * t + 1 < N) offs[2 * t + 1] = excl + a;
  if (t == 1023) offs[N] = part[1023];
}

// ------------- per-edge compute, scattered directly into CSR slot ------------
__global__ void k_edge(const float* __restrict__ pos,
                       const float* __restrict__ shifts,
                       const float* __restrict__ Wemb,
                       const float* __restrict__ War,
                       const int* __restrict__ species,
                       const int* __restrict__ eidx,
                       const int* __restrict__ offs,
                       int* __restrict__ cursor,
                       float* __restrict__ edata,
                       int* __restrict__ esend,
                       int E) {
  __shared__ float war_s[64];
  int t = threadIdx.x;
  if (t < 64) war_s[t] = War[t];
  __syncthreads();
  int e = blockIdx.x * blockDim.x + t;
  if (e >= E) return;
  int s  = eidx[e];
  int rI = eidx[E + e];
  float vx = pos[rI*3+0] - pos[s*3+0] + shifts[e*3+0];
  float vy = pos[rI*3+1] - pos[s*3+1] + shifts[e*3+1];
  float vz = pos[rI*3+2] - pos[s*3+2] + shifts[e*3+2];
  float len = sqrtf(vx*vx + vy*vy + vz*vz);
  float inv = 1.0f / (len + 1e-9f);
  float ux = vx*inv, uy = vy*inv, uz = vz*inv;
  float uu = len * (1.0f/CUTF);
  float u2 = uu*uu, u6 = u2*u2*u2;
  float fcut = (uu < 1.0f) ? (1.0f - 28.0f*u6 + 48.0f*u6*uu - 21.0f*u6*u2) : 0.0f;
  float x = 3.14159265358979f * uu;
  float sn = sinf(x), c2 = 2.0f*cosf(x), snm1 = 0.0f;
  float pref = sqrtf(2.0f/CUTF) / (len + 1e-20f);
  float rad[8];
  float v[48];
  #pragma unroll
  for (int k = 0; k < 8; k++) {
    rad[k] = pref * sn;
    v[k]   = rad[k] * fcut;           // g
    float nxt = c2*sn - snm1; snm1 = sn; sn = nxt;
  }
  #pragma unroll
  for (int b = 0; b < 8; b++) {       // fr = (rad @ W_ar) * fcut
    float a = 0.0f;
    #pragma unroll
    for (int k = 0; k < 8; k++) a += rad[k] * war_s[k*8+b];
    v[8+b] = a * fcut;
  }
  float px2 = ux*ux, py2 = uy*uy, pz2 = uz*uz;
  v[16] = 1.0f; v[17] = ux;     v[18] = uy;     v[19] = uz;
  v[20] = px2;  v[21] = ux*uy;  v[22] = ux*uz;  v[23] = py2;
  v[24] = uy*uz;v[25] = pz2;
  v[26] = px2*ux; v[27] = px2*uy; v[28] = px2*uz; v[29] = ux*py2;
  v[30] = ux*uy*uz; v[31] = ux*pz2; v[32] = py2*uy; v[33] = py2*uz;
  v[34] = uy*pz2; v[35] = pz2*uz;
  int zs = species[s], zr = species[rI];
  float es0 = Wemb[zs*3+0], es1 = Wemb[zs*3+1], es2 = Wemb[zs*3+2];
  float er0 = Wemb[zr*3+0], er1 = Wemb[zr*3+1], er2 = Wemb[zr*3+2];
  v[36] = es0*er0; v[37] = es0*er1; v[38] = es0*er2;
  v[39] = es1*er0; v[40] = es1*er1; v[41] = es1*er2;
  v[42] = es2*er0; v[43] = es2*er1; v[44] = es2*er2;
  v[45] = 0.0f; v[46] = 0.0f; v[47] = 0.0f;
  int slot = atomicAdd(&cursor[rI], 1);
  int dst = offs[rI] + slot;
  float4* eb4 = reinterpret_cast<float4*>(edata + (size_t)dst * 48);
  #pragma unroll
  for (int w = 0; w < 12; w++)
    eb4[w] = make_float4(v[4*w], v[4*w+1], v[4*w+2], v[4*w+3]);
  esend[dst] = s;
}

// ================= FUSED node kernel (cooperative, grid sync) ================
// Phase 1 (per node q=0,1): acc over edges -> Ab (kept in regs) -> Abf2, chi,
// Bsh1[q] (LDS). grid.sync. Phase 2: gather chi/Abf2 of senders -> newA
// (uses reg Ab for mem term) -> Bsh2 -> out (interleaves Bsh1/Bsh2).
__global__ __launch_bounds__(192, 3) void k_nodeF(
    const float* __restrict__ edata, const int* __restrict__ esend,
    const int* __restrict__ offs,
    const float* __restrict__ Wrad, const float* __restrict__ Wmem,
    const float* __restrict__ Wchi,
    uint4* __restrict__ Abf2, float* __restrict__ chi,
    float* __restrict__ out, int N, int G) {
  __shared__ float wr_s[288], wm_s[288];   // [deg][r][b], deg stride 72
  __shared__ float wchi_s[40];             // [b][k]
  __shared__ float Bsh1[2][360];           // phase-1 B for nodes q=0,1
  __shared__ float Bsh2[360];              // phase-2 B scratch (reused per q)
  int t = threadIdx.x;
  for (int i = t; i < 256; i += 192) {
    int d = i >> 6, rm = i & 63;
    wr_s[d*72+rm] = Wrad[i];
    wm_s[d*72+rm] = Wmem[i];
  }
  for (int i = t; i < 40;  i += 192) wchi_s[i] = Wchi[i];
  for (int i = t; i < 720; i += 192) (&Bsh1[0][0])[i] = 0.0f;
  int l = t / 9, c = t - l*9;
  bool act = t < 180;
  int ll = act ? l : 0, cc = act ? c : 0;
  int tt = act ? t : 0;
  int deg = d_DEGS[ll];
  float mlt = d_MULTI[ll];
  int kk1 = 1 + deg;
  __syncthreads();

  float AbK[2][8];                         // statically indexed (unrolled q)
  // ---------------- phase 1 ----------------
  #pragma unroll
  for (int q = 0; q < 2; q++) {
    int n = blockIdx.x + q * G;
    if (n < N) {
      float acc[8];
      #pragma unroll
      for (int r = 0; r < 8; r++) acc[r] = 0.0f;
      int start = offs[n], end = offs[n+1];
      #pragma unroll 4
      for (int j = start; j < end; j++) {
        const float* row = edata + (size_t)j * 48;     // SEQUENTIAL
        float p = row[16+ll] * row[36+cc];
        #pragma unroll
        for (int r = 0; r < 8; r++) acc[r] += row[r] * p;
      }
      const float* wp = &wr_s[deg*72];
      #pragma unroll
      for (int b = 0; b < 8; b++) {
        float a = 0.0f;
        #pragma unroll
        for (int r = 0; r < 8; r++) a += acc[r] * wp[r*8+b];
        AbK[q][b] = a;
      }
      if (act) {
        unsigned int pk[4];
        #pragma unroll
        for (int bp = 0; bp < 4; bp++) {
          __hip_bfloat16 blo = __float2bfloat16(AbK[q][2*bp]);
          __hip_bfloat16 bhi = __float2bfloat16(AbK[q][2*bp+1]);
          pk[bp] = (unsigned int)(*reinterpret_cast<unsigned short*>(&blo))
                 | ((unsigned int)(*reinterpret_cast<unsigned short*>(&bhi)) << 16);
        }
        uint4 qq; qq.x = pk[0]; qq.y = pk[1]; qq.z = pk[2]; qq.w = pk[3];
        Abf2[(size_t)n*180 + t] = qq;
        if (l == 0) {
          #pragma unroll
          for (int b = 0; b < 8; b++) Bsh1[q][b*45 + c] = AbK[q][b];
        }
        #pragma unroll
        for (int b = 0; b < 8; b++)
          atomicAdd(&Bsh1[q][b*45 + kk1*9 + c], mlt*AbK[q][b]*AbK[q][b]);
      }
    }
    __syncthreads();
    if (n < N && t < 9) {
      float s = 0.0f;
      for (int b = 0; b < 8; b++)
        #pragma unroll
        for (int kq = 0; kq < 5; kq++) s += Bsh1[q][b*45 + kq*9 + t] * wchi_s[b*5 + kq];
      chi[n*9 + t] = s;
    }
  }
  __threadfence();
  cg::this_grid().sync();
  // ---------------- phase 2 ----------------
  #pragma unroll
  for (int q = 0; q < 2; q++) {
    int n = blockIdx.x + q * G;
    for (int i = t; i < 360; i += 192) Bsh2[i] = 0.0f;
    __syncthreads();
    if (n < N) {
      float Sacc[8], ARacc[8];
      #pragma unroll
      for (int r = 0; r < 8; r++) { Sacc[r] = 0.0f; ARacc[r] = 0.0f; }
      int start = offs[n], end = offs[n+1];
      #pragma unroll 4
      for (int j = start; j < end; j++) {
        const float* row = edata + (size_t)j * 48;     // SEQUENTIAL
        int snd = esend[j];                            // SEQUENTIAL s_load
        float ch = chi[snd*9 + cc];                    // depth-1 gather
        float pch = row[16+ll] * row[36+cc] * ch;
        #pragma unroll
        for (int r = 0; r < 8; r++) Sacc[r] += row[r] * pch;
        const uint4 qv = Abf2[(size_t)snd*180 + tt];   // depth-1, ONE 16B load
        float a0 = __uint_as_float(qv.x << 16), a1 = __uint_as_float(qv.x & 0xffff0000u);
        float a2 = __uint_as_float(qv.y << 16), a3 = __uint_as_float(qv.y & 0xffff0000u);
        float a4 = __uint_as_float(qv.z << 16), a5 = __uint_as_float(qv.z & 0xffff0000u);
        float a6 = __uint_as_float(qv.w << 16), a7 = __uint_as_float(qv.w & 0xffff0000u);
        ARacc[0] += a0*row[8];  ARacc[1] += a1*row[9];
        ARacc[2] += a2*row[10]; ARacc[3] += a3*row[11];
        ARacc[4] += a4*row[12]; ARacc[5] += a5*row[13];
        ARacc[6] += a6*row[14]; ARacc[7] += a7*row[15];
      }
      if (act) {
        const float* wrp = &wr_s[deg*72];
        const float* wmp = &wm_s[deg*72];
        float newA[8];
        #pragma unroll
        for (int b = 0; b < 8; b++) {
          float mem = 0.0f, ab = 0.0f;
          #pragma unroll
          for (int r = 0; r < 8; r++) { mem += AbK[q][r]*wmp[r*8+b]; ab += Sacc[r]*wrp[r*8+b]; }
          newA[b] = (ARacc[b] + ab)*MPNORM + mem;
        }
        if (l == 0) {
          #pragma unroll
          for (int b = 0; b < 8; b++) Bsh2[b*45 + c] = newA[b];
        }
        #pragma unroll
        for (int b = 0; b < 8; b++)
          atomicAdd(&Bsh2[b*45 + kk1*9 + c], mlt*newA[b]*newA[b]);
      }
    }
    __syncthreads();
    if (n < N) {
      float2* out2 = reinterpret_cast<float2*>(out);
      for (int i = t; i < 360; i += 192) {
        float2 pk2; pk2.x = Bsh1[q][i]; pk2.y = Bsh2[i];
        out2[(size_t)n*360 + i] = pk2;                 // coalesced 8B stores
      }
    }
    __syncthreads();   // Bsh2 reused by next q
  }
}

// ---------------- fallback path (proven r7 kernels) --------------------------
__global__ __launch_bounds__(192) void k_nodeA(
    const float* __restrict__ edata, const int* __restrict__ offs,
    const float* __restrict__ Wrad, const float* __restrict__ Wchi,
    float* __restrict__ A, uint4* __restrict__ Abf2,
    float* __restrict__ chi, float* __restrict__ B0, int N) {
  __shared__ float wr_s[288];
  __shared__ float wchi_s[40];
  __shared__ float Bsh[360];
  int t = threadIdx.x, n = blockIdx.x;
  for (int i = t; i < 256; i += 192) { int d = i >> 6, rm = i & 63; wr_s[d*72+rm] = Wrad[i]; }
  for (int i = t; i < 40;  i += 192) wchi_s[i] = Wchi[i];
  for (int i = t; i < 360; i += 192) Bsh[i] = 0.0f;
  int l = t / 9, c = t - l*9;
  bool act = t < 180;
  int ll = act ? l : 0, cc = act ? c : 0;
  float acc[8];
  #pragma unroll
  for (int r = 0; r < 8; r++) acc[r] = 0.0f;
  int start = offs[n], end = offs[n+1];
  #pragma unroll 4
  for (int j = start; j < end; j++) {
    const float* row = edata + (size_t)j * 48;
    float p = row[16+ll] * row[36+cc];
    #pragma unroll
    for (int r = 0; r < 8; r++) acc[r] += row[r] * p;
  }
  __syncthreads();
  int deg = act ? d_DEGS[ll] : 0;
  const float* wp = &wr_s[deg*72];
  float Ab[8];
  #pragma unroll
  for (int b = 0; b < 8; b++) {
    float a = 0.0f;
    #pragma unroll
    for (int r = 0; r < 8; r++) a += acc[r] * wp[r*8+b];
    Ab[b] = a;
  }
  if (act) {
    #pragma unroll
    for (int b = 0; b < 8; b++) A[(size_t)n*1440 + t*8 + b] = Ab[b];
    unsigned int pk[4];
    #pragma unroll
    for (int bp = 0; bp < 4; bp++) {
      __hip_bfloat16 blo = __float2bfloat16(Ab[2*bp]);
      __hip_bfloat16 bhi = __float2bfloat16(Ab[2*bp+1]);
      pk[bp] = (unsigned int)(*reinterpret_cast<unsigned short*>(&blo))
             | ((unsigned int)(*reinterpret_cast<unsigned short*>(&bhi)) << 16);
    }
    uint4 qv; qv.x = pk[0]; qv.y = pk[1]; qv.z = pk[2]; qv.w = pk[3];
    Abf2[(size_t)n*180 + t] = qv;
    if (l == 0) {
      #pragma unroll
      for (int b = 0; b < 8; b++) Bsh[b*45 + c] = Ab[b];
    }
    float mlt = d_MULTI[ll]; int kk = 1 + deg;
    #pragma unroll
    for (int b = 0; b < 8; b++) atomicAdd(&Bsh[b*45 + kk*9 + c], mlt*Ab[b]*Ab[b]);
  }
  __syncthreads();
  if (t < 9) {
    float s = 0.0f;
    for (int b = 0; b < 8; b++)
      #pragma unroll
      for (int kq = 0; kq < 5; kq++) s += Bsh[b*45 + kq*9 + t] * wchi_s[b*5 + kq];
    chi[n*9 + t] = s;
  }
  for (int i = t; i < 360; i += 192)
    B0[(size_t)n*360 + i] = Bsh[i];
}

__global__ __launch_bounds__(192) void k_node2(
    const float* __restrict__ edata, const int* __restrict__ esend,
    const int* __restrict__ offs,
    const float* __restrict__ Wrad, const float* __restrict__ Wmem,
    const float* __restrict__ A, const uint4* __restrict__ Abf2,
    const float* __restrict__ chi, const float* __restrict__ B0,
    float* __restrict__ out, int N) {
  __shared__ float wr_s[288], wm_s[288];
  __shared__ float Bsh[360];
  int t = threadIdx.x, n = blockIdx.x;
  for (int i = t; i < 256; i += 192) {
    int d = i >> 6, rm = i & 63;
    wr_s[d*72+rm] = Wrad[i];
    wm_s[d*72+rm] = Wmem[i];
  }
  for (int i = t; i < 360; i += 192) Bsh[i] = 0.0f;
  int l = t / 9, c = t - l*9;
  bool act = t < 180;
  int ll = act ? l : 0, cc = act ? c : 0;
  int tt = act ? t : 0;
  float Sacc[8], ARacc[8];
  #pragma unroll
  for (int r = 0; r < 8; r++) { Sacc[r] = 0.0f; ARacc[r] = 0.0f; }
  int start = offs[n], end = offs[n+1];
  #pragma unroll 4
  for (int j = start; j < end; j++) {
    const float* row = edata + (size_t)j * 48;
    int snd = esend[j];
    float ch = chi[snd*9 + cc];
    float pch = row[16+ll] * row[36+cc] * ch;
    #pragma unroll
    for (int r = 0; r < 8; r++) Sacc[r] += row[r] * pch;
    const uint4 qv = Abf2[(size_t)snd*180 + tt];
    float a0 = __uint_as_float(qv.x << 16), a1 = __uint_as_float(qv.x & 0xffff0000u);
    float a2 = __uint_as_float(qv.y << 16), a3 = __uint_as_float(qv.y & 0xffff0000u);
    float a4 = __uint_as_float(qv.z << 16), a5 = __uint_as_float(qv.z & 0xffff0000u);
    float a6 = __uint_as_float(qv.w << 16), a7 = __uint_as_float(qv.w & 0xffff0000u);
    ARacc[0] += a0*row[8];  ARacc[1] += a1*row[9];
    ARacc[2] += a2*row[10]; ARacc[3] += a3*row[11];
    ARacc[4] += a4*row[12]; ARacc[5] += a5*row[13];
    ARacc[6] += a6*row[14]; ARacc[7] += a7*row[15];
  }
  __syncthreads();
  if (act) {
    int deg = d_DEGS[ll];
    const float* wrp = &wr_s[deg*72];
    const float* wmp = &wm_s[deg*72];
    const float* aop = A + (size_t)n*1440 + t*8;
    float aown[8];
    #pragma unroll
    for (int r = 0; r < 8; r++) aown[r] = aop[r];
    float newA[8];
    #pragma unroll
    for (int b = 0; b < 8; b++) {
      float mem = 0.0f, ab = 0.0f;
      #pragma unroll
      for (int r = 0; r < 8; r++) { mem += aown[r]*wmp[r*8+b]; ab += Sacc[r]*wrp[r*8+b]; }
      newA[b] = (ARacc[b] + ab)*MPNORM + mem;
    }
    if (l == 0) {
      #pragma unroll
      for (int b = 0; b < 8; b++) Bsh[b*45 + c] = newA[b];
    }
    float mlt = d_MULTI[ll]; int kk = 1 + deg;
    #pragma unroll
    for (int b = 0; b < 8; b++) atomicAdd(&Bsh[b*45 + kk*9 + c], mlt*newA[b]*newA[b]);
  }
  __syncthreads();
  float2* out2 = reinterpret_cast<float2*>(out);
  for (int i = t; i < 360; i += 192) {
    float2 pk; pk.x = B0[(size_t)n*360 + i]; pk.y = Bsh[i];
    out2[(size_t)n*360 + i] = pk;
  }
}

extern "C" void kernel_launch(void* const* d_in, const int* in_sizes, int n_in,
                              void* d_out, int out_size, void* d_ws, size_t ws_size,
                              hipStream_t stream) {
  const float* pos    = (const float*)d_in[0];
  const float* shifts = (const float*)d_in[1];
  const float* Wemb   = (const float*)d_in[2];
  const float* Wrad   = (const float*)d_in[3];
  const float* Wmem   = (const float*)d_in[4];
  const float* War    = (const float*)d_in[5];
  const float* Wchi   = (const float*)d_in[6];
  const int* species = (const int*)d_in[7];
  const int* eidx    = (const int*)d_in[8];
  float* out = (float*)d_out;
  int N = in_sizes[7];
  int E = in_sizes[8] / 2;

  char* base = (char*)d_ws;
  size_t off = 0;
  float* edata = (float*)(base + off); off += (size_t)E*48*4;          // 9.6 MB (CSR-sorted)
  float* A     = (float*)(base + off); off += (size_t)N*1440*4;        // fallback only
  uint4* Abf2  = (uint4*)(base + off); off += (size_t)N*180*16;        // 5.76 MB packed
  float* chi   = (float*)(base + off); off += (size_t)N*9*4;
  float* B0    = (float*)(base + off); off += (size_t)N*360*4;         // fallback only
  int* cursor  = (int*)(base + off);   off += (size_t)N*4;
  int* offs    = (int*)(base + off);   off += (((size_t)(N+1)*4) + 15) & ~(size_t)15;
  int* esend   = (int*)(base + off);   off += (size_t)E*4;

  int G = (N + 1) / 2;

  // One-time capability check for the cooperative fused path (pure queries,
  // no allocation / sync -> graph-capture safe).
  static int s_coop = -1;
  static int s_G = 0;
  if (s_coop < 0) {
    int dev = 0; hipGetDevice(&dev);
    int nCU = 0;
    hipDeviceGetAttribute(&nCU, hipDeviceAttributeMultiprocessorCount, dev);
    int maxB = 0;
    hipError_t oe = hipOccupancyMaxActiveBlocksPerMultiprocessor(
        &maxB, reinterpret_cast<const void*>(k_nodeF), 192, 0);
    s_coop = (oe == hipSuccess && nCU > 0 && (long)maxB * nCU >= G) ? 1 : 0;
    s_G = G;
  }
  if (s_G != G) s_coop = 0;  // shape changed vs. cached check: be safe

  int eb = (E + 255) / 256;
  k_prep<<<1, 1024, 0, stream>>>(eidx, offs, cursor, N, E);
  k_edge<<<eb, 256, 0, stream>>>(pos, shifts, Wemb, War, species, eidx, offs, cursor,
                                 edata, esend, E);

  bool done = false;
  if (s_coop == 1) {
    void* args[] = {(void*)&edata, (void*)&esend, (void*)&offs,
                    (void*)&Wrad, (void*)&Wmem, (void*)&Wchi,
                    (void*)&Abf2, (void*)&chi, (void*)&out,
                    (void*)&N, (void*)&G};
    hipError_t le = hipLaunchCooperativeKernel(
        reinterpret_cast<void*>(k_nodeF), dim3(G), dim3(192), args, 0, stream);
    if (le == hipSuccess) done = true; else s_coop = 0;
  }
  if (!done) {
    k_nodeA<<<N, 192, 0, stream>>>(edata, offs, Wrad, Wchi, A, Abf2, chi, B0, N);
    k_node2<<<N, 192, 0, stream>>>(edata, esend, offs, Wrad, Wmem, A, Abf2, chi, B0, out, N);
  }
}

// Round 3
// 150.743 us; speedup vs baseline: 1.0084x; 1.0084x over previous
//
#include <hip/hip_runtime.h>
#include <hip/hip_bf16.h>

// CACE message passing, fused. MAX_L=3 -> NL=20, N_RBF=8, RB=8, K=3 -> C=9,
// NB=5, CUTOFF=5.5, T_MP=1, MP_NORM=0.2, N=2000, E=50000. fp32 I/O.
// Round 9 (coop fusion reverted -- r8 measured latency-bound, grid-limited):
//  (a) k_prep assigns per-edge CSR rank via LDS atomic (erank[e]); k_edge's
//      contended global atomicAdd(cursor) eliminated (degree-45 hot nodes
//      serialized ~300cyc/op in its tail).
//  (b) k_edge: 64-thread blocks -> 782 blocks (196 blocks left 60 CUs idle).
//  (c) k_nodeA/k_node2: each block owns ADJACENT node pair (2b, 2b+1) with
//      INTERLEAVED edge loops -> two independent gather chains per thread
//      (2x MLP), contiguous edata streaming, half the blocks/dispatch drain.
// Row (48 floats): [0:8] g, [8:16] fr, [16:36] ang, [36:45] enc, [45:48] pad.
// Edge rows CSR-sorted by recv (k_edge scatters to final slot offs[r]+rank).

#define CUTF 5.5f
#define MPNORM 0.2f

__constant__ int   d_DEGS[20]  = {0,1,1,1,2,2,2,2,2,2,3,3,3,3,3,3,3,3,3,3};
__constant__ float d_MULTI[20] = {1,1,1,1,1,2,2,1,2,1,1,3,3,3,6,3,1,3,3,1};

// ------ count + rank + exclusive scan, one block (N<=2048, 1024 thr) --------
__global__ __launch_bounds__(1024) void k_prep(const int* __restrict__ eidx,
                                               int* __restrict__ offs,
                                               int* __restrict__ erank,
                                               int N, int E) {
  __shared__ int cnt[2048];
  __shared__ int part[1024];
  int t = threadIdx.x;
  cnt[t] = 0; cnt[t + 1024] = 0;
  __syncthreads();
  const int* recv = eidx + E;
  if ((E & 3) == 0) {
    for (int i = t * 4; i + 3 < E; i += 4096) {
      int4 v = *reinterpret_cast<const int4*>(recv + i);
      int r0 = atomicAdd(&cnt[v.x], 1);
      int r1 = atomicAdd(&cnt[v.y], 1);
      int r2 = atomicAdd(&cnt[v.z], 1);
      int r3 = atomicAdd(&cnt[v.w], 1);
      *reinterpret_cast<int4*>(erank + i) = make_int4(r0, r1, r2, r3);
    }
  } else {
    for (int i = t; i < E; i += 1024) erank[i] = atomicAdd(&cnt[recv[i]], 1);
  }
  __syncthreads();
  int a = cnt[2 * t], b = cnt[2 * t + 1];
  int s = a + b;
  part[t] = s;
  __syncthreads();
  for (int d = 1; d < 1024; d <<= 1) {
    int add = (t >= d) ? part[t - d] : 0;
    __syncthreads();
    part[t] += add;
    __syncthreads();
  }
  int excl = part[t] - s;
  if (2 * t     < N) offs[2 * t]     = excl;
  if (2 * t + 1 < N) offs[2 * t + 1] = excl + a;
  if (t == 1023) offs[N] = part[1023];
}

// ------------- per-edge compute, scattered directly into CSR slot ------------
__global__ __launch_bounds__(64) void k_edge(
                       const float* __restrict__ pos,
                       const float* __restrict__ shifts,
                       const float* __restrict__ Wemb,
                       const float* __restrict__ War,
                       const int* __restrict__ species,
                       const int* __restrict__ eidx,
                       const int* __restrict__ offs,
                       const int* __restrict__ erank,
                       float* __restrict__ edata,
                       int* __restrict__ esend,
                       int E) {
  __shared__ float war_s[64];
  int t = threadIdx.x;
  war_s[t] = War[t];
  __syncthreads();
  int e = blockIdx.x * 64 + t;
  if (e >= E) return;
  int s  = eidx[e];
  int rI = eidx[E + e];
  int rk = erank[e];
  float vx = pos[rI*3+0] - pos[s*3+0] + shifts[e*3+0];
  float vy = pos[rI*3+1] - pos[s*3+1] + shifts[e*3+1];
  float vz = pos[rI*3+2] - pos[s*3+2] + shifts[e*3+2];
  float len = sqrtf(vx*vx + vy*vy + vz*vz);
  float inv = 1.0f / (len + 1e-9f);
  float ux = vx*inv, uy = vy*inv, uz = vz*inv;
  float uu = len * (1.0f/CUTF);
  float u2 = uu*uu, u6 = u2*u2*u2;
  float fcut = (uu < 1.0f) ? (1.0f - 28.0f*u6 + 48.0f*u6*uu - 21.0f*u6*u2) : 0.0f;
  float x = 3.14159265358979f * uu;
  float sn = sinf(x), c2 = 2.0f*cosf(x), snm1 = 0.0f;
  float pref = sqrtf(2.0f/CUTF) / (len + 1e-20f);
  float rad[8];
  float v[48];
  #pragma unroll
  for (int k = 0; k < 8; k++) {
    rad[k] = pref * sn;
    v[k]   = rad[k] * fcut;           // g
    float nxt = c2*sn - snm1; snm1 = sn; sn = nxt;
  }
  #pragma unroll
  for (int b = 0; b < 8; b++) {       // fr = (rad @ W_ar) * fcut
    float a = 0.0f;
    #pragma unroll
    for (int k = 0; k < 8; k++) a += rad[k] * war_s[k*8+b];
    v[8+b] = a * fcut;
  }
  float px2 = ux*ux, py2 = uy*uy, pz2 = uz*uz;
  v[16] = 1.0f; v[17] = ux;     v[18] = uy;     v[19] = uz;
  v[20] = px2;  v[21] = ux*uy;  v[22] = ux*uz;  v[23] = py2;
  v[24] = uy*uz;v[25] = pz2;
  v[26] = px2*ux; v[27] = px2*uy; v[28] = px2*uz; v[29] = ux*py2;
  v[30] = ux*uy*uz; v[31] = ux*pz2; v[32] = py2*uy; v[33] = py2*uz;
  v[34] = uy*pz2; v[35] = pz2*uz;
  int zs = species[s], zr = species[rI];
  float es0 = Wemb[zs*3+0], es1 = Wemb[zs*3+1], es2 = Wemb[zs*3+2];
  float er0 = Wemb[zr*3+0], er1 = Wemb[zr*3+1], er2 = Wemb[zr*3+2];
  v[36] = es0*er0; v[37] = es0*er1; v[38] = es0*er2;
  v[39] = es1*er0; v[40] = es1*er1; v[41] = es1*er2;
  v[42] = es2*er0; v[43] = es2*er1; v[44] = es2*er2;
  v[45] = 0.0f; v[46] = 0.0f; v[47] = 0.0f;
  int dst = offs[rI] + rk;
  float4* eb4 = reinterpret_cast<float4*>(edata + (size_t)dst * 48);
  #pragma unroll
  for (int w = 0; w < 12; w++)
    eb4[w] = make_float4(v[4*w], v[4*w+1], v[4*w+2], v[4*w+3]);
  esend[dst] = s;
}

// --------- per-node phase 1 (node PAIR per block, interleaved loops) ---------
// nodes n0=2*bid, n1=2*bid+1; thread t<180 owns (l=t/9, c=t%9).
__global__ __launch_bounds__(192) void k_nodeA(
    const float* __restrict__ edata, const int* __restrict__ offs,
    const float* __restrict__ Wrad, const float* __restrict__ Wchi,
    float* __restrict__ A, uint4* __restrict__ Abf2,
    float* __restrict__ chi, float* __restrict__ B0, int N) {
  __shared__ float wr_s[288];        // [deg][r][b], deg stride 72
  __shared__ float wchi_s[40];       // [b][k]
  __shared__ float Bsh[2][360];      // [q][b*45 + k*9 + c]
  int t = threadIdx.x;
  int n0 = blockIdx.x * 2, n1 = n0 + 1;
  for (int i = t; i < 256; i += 192) { int d = i >> 6, rm = i & 63; wr_s[d*72+rm] = Wrad[i]; }
  for (int i = t; i < 40;  i += 192) wchi_s[i] = Wchi[i];
  for (int i = t; i < 720; i += 192) (&Bsh[0][0])[i] = 0.0f;
  int l = t / 9, c = t - l*9;
  bool act = t < 180;
  int ll = act ? l : 0, cc = act ? c : 0;
  int s0 = offs[n0], m0 = offs[n0+1];
  int m1 = (n1 < N) ? offs[n0+2] : m0;
  int L0 = m0 - s0, L1 = m1 - m0;
  int Lc = (L0 < L1) ? L0 : L1;
  float acc0[8], acc1[8];
  #pragma unroll
  for (int r = 0; r < 8; r++) { acc0[r] = 0.0f; acc1[r] = 0.0f; }
  // interleaved common part: two independent chains -> 2x MLP
  #pragma unroll 2
  for (int i = 0; i < Lc; i++) {
    const float* r0 = edata + (size_t)(s0+i) * 48;
    const float* r1 = edata + (size_t)(m0+i) * 48;
    float p0 = r0[16+ll] * r0[36+cc];
    float p1 = r1[16+ll] * r1[36+cc];
    #pragma unroll
    for (int r = 0; r < 8; r++) { acc0[r] += r0[r] * p0; acc1[r] += r1[r] * p1; }
  }
  #pragma unroll 4
  for (int i = Lc; i < L0; i++) {
    const float* r0 = edata + (size_t)(s0+i) * 48;
    float p0 = r0[16+ll] * r0[36+cc];
    #pragma unroll
    for (int r = 0; r < 8; r++) acc0[r] += r0[r] * p0;
  }
  #pragma unroll 4
  for (int i = Lc; i < L1; i++) {
    const float* r1 = edata + (size_t)(m0+i) * 48;
    float p1 = r1[16+ll] * r1[36+cc];
    #pragma unroll
    for (int r = 0; r < 8; r++) acc1[r] += r1[r] * p1;
  }
  __syncthreads();   // weights/Bsh zeros visible
  int deg = act ? d_DEGS[ll] : 0;
  float mlt = d_MULTI[ll]; int kk = 1 + deg;
  const float* wp = &wr_s[deg*72];
  #pragma unroll
  for (int q = 0; q < 2; q++) {
    int n = n0 + q;
    if (n >= N) break;
    const float* ac = q ? acc1 : acc0;
    float Ab[8];
    #pragma unroll
    for (int b = 0; b < 8; b++) {
      float a = 0.0f;
      #pragma unroll
      for (int r = 0; r < 8; r++) a += ac[r] * wp[r*8+b];
      Ab[b] = a;
    }
    if (act) {
      #pragma unroll
      for (int b = 0; b < 8; b++) A[(size_t)n*1440 + t*8 + b] = Ab[b];
      unsigned int pk[4];
      #pragma unroll
      for (int bp = 0; bp < 4; bp++) {
        __hip_bfloat16 blo = __float2bfloat16(Ab[2*bp]);
        __hip_bfloat16 bhi = __float2bfloat16(Ab[2*bp+1]);
        pk[bp] = (unsigned int)(*reinterpret_cast<unsigned short*>(&blo))
               | ((unsigned int)(*reinterpret_cast<unsigned short*>(&bhi)) << 16);
      }
      uint4 qv; qv.x = pk[0]; qv.y = pk[1]; qv.z = pk[2]; qv.w = pk[3];
      Abf2[(size_t)n*180 + t] = qv;
      if (l == 0) {
        #pragma unroll
        for (int b = 0; b < 8; b++) Bsh[q][b*45 + c] = Ab[b];
      }
      #pragma unroll
      for (int b = 0; b < 8; b++) atomicAdd(&Bsh[q][b*45 + kk*9 + c], mlt*Ab[b]*Ab[b]);
    }
  }
  __syncthreads();
  if (t < 18) {
    int q = t / 9, tc = t - q*9;
    int n = n0 + q;
    if (n < N) {
      float s = 0.0f;
      for (int b = 0; b < 8; b++)
        #pragma unroll
        for (int kq = 0; kq < 5; kq++) s += Bsh[q][b*45 + kq*9 + tc] * wchi_s[b*5 + kq];
      chi[n*9 + tc] = s;
    }
  }
  int tot = (n1 < N) ? 720 : 360;
  for (int i = t; i < tot; i += 192)
    B0[(size_t)n0*360 + i] = (&Bsh[0][0])[i];   // contiguous, coalesced
}

// --------- per-node phase 2 (node PAIR per block, interleaved loops) ---------
__global__ __launch_bounds__(192) void k_node2(
    const float* __restrict__ edata, const int* __restrict__ esend,
    const int* __restrict__ offs,
    const float* __restrict__ Wrad, const float* __restrict__ Wmem,
    const float* __restrict__ A, const uint4* __restrict__ Abf2,
    const float* __restrict__ chi, const float* __restrict__ B0,
    float* __restrict__ out, int N) {
  __shared__ float wr_s[288], wm_s[288];
  __shared__ float Bsh[2][360];
  int t = threadIdx.x;
  int n0 = blockIdx.x * 2, n1 = n0 + 1;
  for (int i = t; i < 256; i += 192) {
    int d = i >> 6, rm = i & 63;
    wr_s[d*72+rm] = Wrad[i];
    wm_s[d*72+rm] = Wmem[i];
  }
  for (int i = t; i < 720; i += 192) (&Bsh[0][0])[i] = 0.0f;
  int l = t / 9, c = t - l*9;
  bool act = t < 180;
  int ll = act ? l : 0, cc = act ? c : 0;
  int tt = act ? t : 0;
  int s0 = offs[n0], m0 = offs[n0+1];
  int m1 = (n1 < N) ? offs[n0+2] : m0;
  int L0 = m0 - s0, L1 = m1 - m0;
  int Lc = (L0 < L1) ? L0 : L1;
  float S0[8], R0[8], S1[8], R1[8];
  #pragma unroll
  for (int r = 0; r < 8; r++) { S0[r]=0.0f; R0[r]=0.0f; S1[r]=0.0f; R1[r]=0.0f; }
  #pragma unroll 2
  for (int i = 0; i < Lc; i++) {
    int j0 = s0 + i, j1 = m0 + i;
    const float* r0 = edata + (size_t)j0 * 48;
    const float* r1 = edata + (size_t)j1 * 48;
    int sd0 = esend[j0], sd1 = esend[j1];
    float ch0 = chi[sd0*9 + cc], ch1 = chi[sd1*9 + cc];
    const uint4 q0 = Abf2[(size_t)sd0*180 + tt];
    const uint4 q1 = Abf2[(size_t)sd1*180 + tt];
    float pc0 = r0[16+ll] * r0[36+cc] * ch0;
    float pc1 = r1[16+ll] * r1[36+cc] * ch1;
    #pragma unroll
    for (int r = 0; r < 8; r++) { S0[r] += r0[r] * pc0; S1[r] += r1[r] * pc1; }
    float a0 = __uint_as_float(q0.x << 16), a1 = __uint_as_float(q0.x & 0xffff0000u);
    float a2 = __uint_as_float(q0.y << 16), a3 = __uint_as_float(q0.y & 0xffff0000u);
    float a4 = __uint_as_float(q0.z << 16), a5 = __uint_as_float(q0.z & 0xffff0000u);
    float a6 = __uint_as_float(q0.w << 16), a7 = __uint_as_float(q0.w & 0xffff0000u);
    R0[0] += a0*r0[8];  R0[1] += a1*r0[9];  R0[2] += a2*r0[10]; R0[3] += a3*r0[11];
    R0[4] += a4*r0[12]; R0[5] += a5*r0[13]; R0[6] += a6*r0[14]; R0[7] += a7*r0[15];
    float b0 = __uint_as_float(q1.x << 16), b1 = __uint_as_float(q1.x & 0xffff0000u);
    float b2 = __uint_as_float(q1.y << 16), b3 = __uint_as_float(q1.y & 0xffff0000u);
    float b4 = __uint_as_float(q1.z << 16), b5 = __uint_as_float(q1.z & 0xffff0000u);
    float b6 = __uint_as_float(q1.w << 16), b7 = __uint_as_float(q1.w & 0xffff0000u);
    R1[0] += b0*r1[8];  R1[1] += b1*r1[9];  R1[2] += b2*r1[10]; R1[3] += b3*r1[11];
    R1[4] += b4*r1[12]; R1[5] += b5*r1[13]; R1[6] += b6*r1[14]; R1[7] += b7*r1[15];
  }
  #pragma unroll 4
  for (int i = Lc; i < L0; i++) {
    int j0 = s0 + i;
    const float* r0 = edata + (size_t)j0 * 48;
    int sd0 = esend[j0];
    float ch0 = chi[sd0*9 + cc];
    const uint4 q0 = Abf2[(size_t)sd0*180 + tt];
    float pc0 = r0[16+ll] * r0[36+cc] * ch0;
    #pragma unroll
    for (int r = 0; r < 8; r++) S0[r] += r0[r] * pc0;
    float a0 = __uint_as_float(q0.x << 16), a1 = __uint_as_float(q0.x & 0xffff0000u);
    float a2 = __uint_as_float(q0.y << 16), a3 = __uint_as_float(q0.y & 0xffff0000u);
    float a4 = __uint_as_float(q0.z << 16), a5 = __uint_as_float(q0.z & 0xffff0000u);
    float a6 = __uint_as_float(q0.w << 16), a7 = __uint_as_float(q0.w & 0xffff0000u);
    R0[0] += a0*r0[8];  R0[1] += a1*r0[9];  R0[2] += a2*r0[10]; R0[3] += a3*r0[11];
    R0[4] += a4*r0[12]; R0[5] += a5*r0[13]; R0[6] += a6*r0[14]; R0[7] += a7*r0[15];
  }
  #pragma unroll 4
  for (int i = Lc; i < L1; i++) {
    int j1 = m0 + i;
    const float* r1 = edata + (size_t)j1 * 48;
    int sd1 = esend[j1];
    float ch1 = chi[sd1*9 + cc];
    const uint4 q1 = Abf2[(size_t)sd1*180 + tt];
    float pc1 = r1[16+ll] * r1[36+cc] * ch1;
    #pragma unroll
    for (int r = 0; r < 8; r++) S1[r] += r1[r] * pc1;
    float b0 = __uint_as_float(q1.x << 16), b1 = __uint_as_float(q1.x & 0xffff0000u);
    float b2 = __uint_as_float(q1.y << 16), b3 = __uint_as_float(q1.y & 0xffff0000u);
    float b4 = __uint_as_float(q1.z << 16), b5 = __uint_as_float(q1.z & 0xffff0000u);
    float b6 = __uint_as_float(q1.w << 16), b7 = __uint_as_float(q1.w & 0xffff0000u);
    R1[0] += b0*r1[8];  R1[1] += b1*r1[9];  R1[2] += b2*r1[10]; R1[3] += b3*r1[11];
    R1[4] += b4*r1[12]; R1[5] += b5*r1[13]; R1[6] += b6*r1[14]; R1[7] += b7*r1[15];
  }
  __syncthreads();
  int deg = act ? d_DEGS[ll] : 0;
  float mlt = d_MULTI[ll]; int kk = 1 + deg;
  const float* wrp = &wr_s[deg*72];
  const float* wmp = &wm_s[deg*72];
  #pragma unroll
  for (int q = 0; q < 2; q++) {
    int n = n0 + q;
    if (n >= N) break;
    if (act) {
      const float* Sq = q ? S1 : S0;
      const float* Rq = q ? R1 : R0;
      const float* aop = A + (size_t)n*1440 + t*8;
      float aown[8];
      #pragma unroll
      for (int r = 0; r < 8; r++) aown[r] = aop[r];
      float newA[8];
      #pragma unroll
      for (int b = 0; b < 8; b++) {
        float mem = 0.0f, ab = 0.0f;
        #pragma unroll
        for (int r = 0; r < 8; r++) { mem += aown[r]*wmp[r*8+b]; ab += Sq[r]*wrp[r*8+b]; }
        newA[b] = (Rq[b] + ab)*MPNORM + mem;
      }
      if (l == 0) {
        #pragma unroll
        for (int b = 0; b < 8; b++) Bsh[q][b*45 + c] = newA[b];
      }
      #pragma unroll
      for (int b = 0; b < 8; b++) atomicAdd(&Bsh[q][b*45 + kk*9 + c], mlt*newA[b]*newA[b]);
    }
  }
  __syncthreads();
  float2* out2 = reinterpret_cast<float2*>(out);
  int tot = (n1 < N) ? 720 : 360;
  for (int i = t; i < tot; i += 192) {
    float2 pk;
    pk.x = B0[(size_t)n0*360 + i];
    pk.y = (&Bsh[0][0])[i];
    out2[(size_t)n0*360 + i] = pk;              // coalesced 8B stores
  }
}

extern "C" void kernel_launch(void* const* d_in, const int* in_sizes, int n_in,
                              void* d_out, int out_size, void* d_ws, size_t ws_size,
                              hipStream_t stream) {
  const float* pos    = (const float*)d_in[0];
  const float* shifts = (const float*)d_in[1];
  const float* Wemb   = (const float*)d_in[2];
  const float* Wrad   = (const float*)d_in[3];
  const float* Wmem   = (const float*)d_in[4];
  const float* War    = (const float*)d_in[5];
  const float* Wchi   = (const float*)d_in[6];
  const int* species = (const int*)d_in[7];
  const int* eidx    = (const int*)d_in[8];
  float* out = (float*)d_out;
  int N = in_sizes[7];
  int E = in_sizes[8] / 2;

  char* base = (char*)d_ws;
  size_t off = 0;
  float* edata = (float*)(base + off); off += (size_t)E*48*4;          // 9.6 MB (CSR-sorted)
  float* A     = (float*)(base + off); off += (size_t)N*1440*4;        // 11.52 MB
  uint4* Abf2  = (uint4*)(base + off); off += (size_t)N*180*16;        // 5.76 MB packed
  float* chi   = (float*)(base + off); off += (size_t)N*9*4;
  float* B0    = (float*)(base + off); off += (size_t)N*360*4;         // 2.88 MB
  int* offs    = (int*)(base + off);   off += (((size_t)(N+1)*4) + 15) & ~(size_t)15;
  int* esend   = (int*)(base + off);   off += (size_t)E*4;
  int* erank   = (int*)(base + off);   off += (((size_t)E*4) + 15) & ~(size_t)15;

  int G = (N + 1) / 2;
  k_prep<<<1, 1024, 0, stream>>>(eidx, offs, erank, N, E);
  k_edge<<<(E + 63) / 64, 64, 0, stream>>>(pos, shifts, Wemb, War, species, eidx,
                                           offs, erank, edata, esend, E);
  k_nodeA<<<G, 192, 0, stream>>>(edata, offs, Wrad, Wchi, A, Abf2, chi, B0, N);
  k_node2<<<G, 192, 0, stream>>>(edata, esend, offs, Wrad, Wmem, A, Abf2, chi, B0, out, N);
}